// Round 5
// baseline (13017.548 us; speedup 1.0000x reference)
//
#include <hip/hip_runtime.h>
#include <math.h>

#define NWG 65
#define KD 256
#define UD 64
#define XD 128
#define TH 200

// ws float offsets
#define OFF_V     0        // 65536
#define OFF_WA    65536    // 65536  WA = V@A
#define OFF_H     131072   // 65536  H = At@WA
#define OFF_G     196608   // 16384  G = Bt@WA (64x256)
#define OFF_K0    212992   // 16384
#define OFF_MI    229376   // 4096   M^-1
#define OFF_MP    233472   // 8*4096 M partials
#define OFF_v     266240
#define OFF_ATV   266496
#define OFF_Z     266752
#define OFF_QG    266816
#define OFF_QD    267072
#define OFF_RD    267328
#define OFF_KV    267392
#define OFF_CV    267456
#define OFF_NKT   267520   // 8192
#define OFF_FLAGS 275712   // unsigned[65*16]

// Coherent (agent-scope, write-through) store: bypasses the XCD L2 so the
// grid barrier never needs a buffer_wbl2 walk. ALL cross-WG global writes in
// k_ric MUST use this.
__device__ __forceinline__ void cst(float* p, float v) {
  __hip_atomic_store(p, v, __ATOMIC_RELAXED, __HIP_MEMORY_SCOPE_AGENT);
}

// Grid barrier, fence-light:
//  release = s_waitcnt vmcnt(0) (coherent stores acked at L3) + relaxed flag
//  poll    = relaxed agent loads (no cache-op per poll)
//  acquire = one agent acquire fence -> buffer_inv only (L2 never dirty)
__device__ __forceinline__ void gbar(unsigned* flags, unsigned ep) {
  asm volatile("s_waitcnt vmcnt(0)" ::: "memory");
  __syncthreads();
  if (threadIdx.x == 0)
    __hip_atomic_store(&flags[blockIdx.x * 16], ep, __ATOMIC_RELAXED, __HIP_MEMORY_SCOPE_AGENT);
  if (threadIdx.x < NWG) {
    while (__hip_atomic_load(&flags[threadIdx.x * 16], __ATOMIC_RELAXED, __HIP_MEMORY_SCOPE_AGENT) < ep)
      __builtin_amdgcn_s_sleep(1);
  }
  __syncthreads();
  __builtin_amdgcn_fence(__ATOMIC_ACQUIRE, "agent");
  __syncthreads();
}

__global__ void k_zero(float* ws) {
  unsigned* f = (unsigned*)(ws + OFF_FLAGS);
  for (int i = threadIdx.x; i < 1088; i += 256) f[i] = 0u;
}

// in-place 4x4 inverse, unpivoted GJ (principal block of SPD matrix)
__device__ __forceinline__ void inv4(float* D) {
#pragma unroll
  for (int p = 0; p < 4; ++p) {
    float ip = 1.0f / D[p * 4 + p];
#pragma unroll
    for (int i2 = 0; i2 < 4; ++i2)
      if (i2 != p) {
        float f = D[i2 * 4 + p] * ip;
#pragma unroll
        for (int j = 0; j < 4; ++j)
          if (j != p) D[i2 * 4 + j] -= f * D[p * 4 + j];
        D[i2 * 4 + p] = -f;
      }
#pragma unroll
    for (int j = 0; j < 4; ++j)
      if (j != p) D[p * 4 + j] *= ip;
    D[p * 4 + p] = ip;
  }
}

#define R16(OP) OP(0) OP(1) OP(2) OP(3) OP(4) OP(5) OP(6) OP(7) OP(8) OP(9) OP(10) OP(11) OP(12) OP(13) OP(14) OP(15)

__global__ __launch_bounds__(256, 1) void k_ric(
    const float* __restrict__ A, const float* __restrict__ B,
    const float* __restrict__ W, const float* __restrict__ bphi,
    const float* __restrict__ xg, const float* __restrict__ qlog,
    const float* __restrict__ rlog, float* __restrict__ ws)
{
  const int w = blockIdx.x;
  const int t = threadIdx.x;
  const int u = w - 1;               // worker id 0..63 (w>=1); WG0 = inverter

  float* V    = ws + OFF_V;
  float* WAg  = ws + OFF_WA;
  float* Hm   = ws + OFF_H;
  float* Gm   = ws + OFF_G;
  float* K0   = ws + OFF_K0;
  float* MI   = ws + OFF_MI;
  float* Mpart= ws + OFF_MP;
  float* vv   = ws + OFF_v;
  float* Atv  = ws + OFF_ATV;
  float* Zv   = ws + OFF_Z;
  float* Qg   = ws + OFF_QG;
  float* Qd   = ws + OFF_QD;
  float* Rd   = ws + OFF_RD;
  float* Kv   = ws + OFF_KV;
  float* Cv   = ws + OFF_CV;
  float* NKT  = ws + OFF_NKT;
  unsigned* flags = (unsigned*)(ws + OFF_FLAGS);

  __shared__ float sA[256 * 36];     // A[p][cb0+r]
  __shared__ float sBsl[256 * 9];    // B[p][m0+j]
  __shared__ float sBr[32 * 64];     // B[rb+r][a]
  __shared__ float svv[256];
  __shared__ float sVB[32 * 9];
  __shared__ float sQd[32];
  __shared__ float sZ[64];
  __shared__ float sRed[8 * 36];
  __shared__ float scr[10880];       // phase-union scratch

  const int sb  = u & 7,  hb = u >> 3;   // valid for w>=1
  const int rb  = sb * 32;               // PhA V col-strip; PhB WA col strip; PhC col strip
  const int cb0 = hb * 32;               // A col strip = H row strip; PhC row strip
  const int m0  = hb * 8;                // B col slice = G row slice

  unsigned ep = 0;

  // ---------------- init ----------------
  if (w < 64) {
    for (int rr2 = 0; rr2 < 4; ++rr2) {
      int r = 4 * w + rr2;
      cst(&V[r * KD + t], (r == t) ? expf(qlog[r]) : 0.f);
    }
  }
  if (w < 4 && t < 64) {
    int i = w * 64 + t;
    float acc = 0.f;
    for (int p = 0; p < XD; ++p) acc = fmaf(W[i * XD + p], xg[p], acc);
    float g = acc + bphi[i];
    float qd = expf(qlog[i]);
    cst(&Qd[i], qd); cst(&Qg[i], qd * g); cst(&vv[i], qd * g);
  }
  if (w == 4 && t < UD) cst(&Rd[t], expf(rlog[t]));
  if (w >= 1) {
    for (int q = 0; q < 32; ++q) { int idx = q * 256 + t; int p = idx >> 5, r = idx & 31; sA[p * 36 + r] = A[p * KD + cb0 + r]; }
    for (int q = 0; q < 8;  ++q) { int idx = q * 256 + t; int p = idx >> 3, j = idx & 7;  sBsl[p * 9 + j] = B[p * UD + m0 + j]; }
    for (int q = 0; q < 8;  ++q) { int idx = q * 256 + t; int r = idx >> 6, a = idx & 63; sBr[r * 64 + a] = B[(rb + r) * UD + a]; }
  }
  gbar(flags, ++ep);
  if (w >= 1 && t < 32) sQd[t] = Qd[cb0 + t];   // rb2 = cb0
  float rdi = (w == 0) ? Rd[t & 63] : 0.f;

  for (int it = 0; it < TH; ++it) {
    // =========== PhA: WA tile + VB sub + M-partial + Atv/z ===========
    if (w >= 1) {
      // V is symmetric: needed row-strip V[rb+r][p] == column-strip V[p][rb+r].
      // Stage row-major (aligned float4 LDS writes, conflict-free).
      float* sVt = scr;   // [256][36]: sVt[p][r] = V[p][rb+r]
      for (int q = 0; q < 8; ++q) {
        int idx = q * 256 + t;
        int p = idx >> 3, r4 = (idx & 7) * 4;
        *(float4*)&sVt[p * 36 + r4] = *(const float4*)(V + p * KD + rb + r4);
      }
      svv[t] = vv[t];
      __syncthreads();

      const int j = t & 31, rq = t >> 5;      // col j, rows 4rq..4rq+3
      float4 acc = {0.f, 0.f, 0.f, 0.f};
      float avb0 = 0.f, avb1 = 0.f, avb2 = 0.f, avb3 = 0.f;
      const bool dovb = (j < 8);
#pragma unroll 8
      for (int p = 0; p < KD; ++p) {
        float4 v4 = *(const float4*)&sVt[p * 36 + rq * 4];
        float a = sA[p * 36 + j];
        acc.x = fmaf(v4.x, a, acc.x);
        acc.y = fmaf(v4.y, a, acc.y);
        acc.z = fmaf(v4.z, a, acc.z);
        acc.w = fmaf(v4.w, a, acc.w);
        if (dovb) {
          float b = sBsl[p * 9 + j];
          avb0 = fmaf(v4.x, b, avb0);
          avb1 = fmaf(v4.y, b, avb1);
          avb2 = fmaf(v4.z, b, avb2);
          avb3 = fmaf(v4.w, b, avb3);
        }
      }
      cst(&WAg[(rb + 4 * rq + 0) * KD + cb0 + j], acc.x);
      cst(&WAg[(rb + 4 * rq + 1) * KD + cb0 + j], acc.y);
      cst(&WAg[(rb + 4 * rq + 2) * KD + cb0 + j], acc.z);
      cst(&WAg[(rb + 4 * rq + 3) * KD + cb0 + j], acc.w);
      if (dovb) {
        sVB[(4 * rq + 0) * 9 + j] = avb0;
        sVB[(4 * rq + 1) * 9 + j] = avb1;
        sVB[(4 * rq + 2) * 9 + j] = avb2;
        sVB[(4 * rq + 3) * 9 + j] = avb3;
      }
      if (sb == 0) {                     // Atv partials
        int c = t & 31, part = t >> 5;
        float acc2 = 0.f;
#pragma unroll 8
        for (int p = part * 32; p < part * 32 + 32; ++p) acc2 = fmaf(sA[p * 36 + c], svv[p], acc2);
        sRed[part * 36 + c] = acc2;
      }
      if (sb == 1 && t < 64) {           // z partials
        int jz = t & 7, part = t >> 3;
        float acc2 = 0.f;
#pragma unroll 8
        for (int p = part * 32; p < part * 32 + 32; ++p) acc2 = fmaf(sBsl[p * 9 + jz], svv[p], acc2);
        sRed[part * 36 + jz] = acc2;
      }
      __syncthreads();
      {  // M-partial: Mp[a][m0+j] = sum_r Br[r][a]*VB[r][j]
        int a = t & 63, j2 = (t >> 6) * 2;
        float mp0 = 0.f, mp1 = 0.f;
#pragma unroll 8
        for (int r = 0; r < 32; ++r) {
          float bv = sBr[r * 64 + a];
          mp0 = fmaf(bv, sVB[r * 9 + j2 + 0], mp0);
          mp1 = fmaf(bv, sVB[r * 9 + j2 + 1], mp1);
        }
        cst(&Mpart[sb * 4096 + a * 64 + m0 + j2 + 0], mp0);
        cst(&Mpart[sb * 4096 + a * 64 + m0 + j2 + 1], mp1);
      }
      if (sb == 0 && t < 32) {
        float a2 = 0.f;
#pragma unroll
        for (int pt = 0; pt < 8; ++pt) a2 += sRed[pt * 36 + t];
        cst(&Atv[cb0 + t], a2);
      }
      if (sb == 1 && t < 8) {
        float a2 = 0.f;
#pragma unroll
        for (int pt = 0; pt < 8; ++pt) a2 += sRed[pt * 36 + t];
        cst(&Zv[m0 + t], a2);
      }
    }
    gbar(flags, ++ep);

    // =========== PhB: WG0 rank-4 register GJ inverse; workers: H + G ===========
    if (w == 0) {
      float* sPR = scr;            // [4][68]
      float* sF  = scr + 280;      // [64][5]
      float* wred= scr + 608;      // [64][4]
      const int i = t & 63, cg = t >> 6;
      float rr[16];
      {
        float4 s0 = {0,0,0,0}, s1 = {0,0,0,0}, s2 = {0,0,0,0}, s3 = {0,0,0,0};
#pragma unroll
        for (int sb2 = 0; sb2 < 8; ++sb2) {
          const float* mp = Mpart + sb2 * 4096 + i * 64 + cg * 16;
          float4 a0 = *(const float4*)(mp + 0);
          float4 a1 = *(const float4*)(mp + 4);
          float4 a2 = *(const float4*)(mp + 8);
          float4 a3 = *(const float4*)(mp + 12);
          s0.x += a0.x; s0.y += a0.y; s0.z += a0.z; s0.w += a0.w;
          s1.x += a1.x; s1.y += a1.y; s1.z += a1.z; s1.w += a1.w;
          s2.x += a2.x; s2.y += a2.y; s2.z += a2.z; s2.w += a2.w;
          s3.x += a3.x; s3.y += a3.y; s3.z += a3.z; s3.w += a3.w;
        }
        rr[0]=s0.x; rr[1]=s0.y; rr[2]=s0.z; rr[3]=s0.w;
        rr[4]=s1.x; rr[5]=s1.y; rr[6]=s1.z; rr[7]=s1.w;
        rr[8]=s2.x; rr[9]=s2.y; rr[10]=s2.z; rr[11]=s2.w;
        rr[12]=s3.x; rr[13]=s3.y; rr[14]=s3.z; rr[15]=s3.w;
#define DIAG(j) rr[j] += (cg * 16 + j == i) ? rdi : 0.f;
        R16(DIAG)
#undef DIAG
      }
      for (int k = 0; k < 16; ++k) {
        const int prw = i - 4 * k;
        const bool inblk = (unsigned)prw < 4u;
        if (inblk) {
#define ST(j) sPR[prw * 68 + cg * 16 + j] = rr[j];
          R16(ST)
#undef ST
        }
        if (cg == (k >> 2)) {
          switch (k & 3) {
            case 0: sF[i*5+0]=rr[0];  sF[i*5+1]=rr[1];  sF[i*5+2]=rr[2];  sF[i*5+3]=rr[3];  break;
            case 1: sF[i*5+0]=rr[4];  sF[i*5+1]=rr[5];  sF[i*5+2]=rr[6];  sF[i*5+3]=rr[7];  break;
            case 2: sF[i*5+0]=rr[8];  sF[i*5+1]=rr[9];  sF[i*5+2]=rr[10]; sF[i*5+3]=rr[11]; break;
            default:sF[i*5+0]=rr[12]; sF[i*5+1]=rr[13]; sF[i*5+2]=rr[14]; sF[i*5+3]=rr[15]; break;
          }
        }
        __syncthreads();
        float D[16];
#pragma unroll
        for (int q = 0; q < 4; ++q) {
          D[q*4+0] = sPR[q*68 + 4*k + 0];
          D[q*4+1] = sPR[q*68 + 4*k + 1];
          D[q*4+2] = sPR[q*68 + 4*k + 2];
          D[q*4+3] = sPR[q*68 + 4*k + 3];
        }
        inv4(D);
        float f0 = sF[i*5+0], f1 = sF[i*5+1], f2 = sF[i*5+2], f3 = sF[i*5+3];
        float g0, g1, g2, g3;
        if (inblk) {
          g0 = prw==0?D[0]:prw==1?D[4]:prw==2?D[8]:D[12];
          g1 = prw==0?D[1]:prw==1?D[5]:prw==2?D[9]:D[13];
          g2 = prw==0?D[2]:prw==1?D[6]:prw==2?D[10]:D[14];
          g3 = prw==0?D[3]:prw==1?D[7]:prw==2?D[11]:D[15];
        } else {
          g0 = f0*D[0] + f1*D[4] + f2*D[8]  + f3*D[12];
          g1 = f0*D[1] + f1*D[5] + f2*D[9]  + f3*D[13];
          g2 = f0*D[2] + f1*D[6] + f2*D[10] + f3*D[14];
          g3 = f0*D[3] + f1*D[7] + f2*D[11] + f3*D[15];
        }
#define CHUNK(c4)                                                         \
        {                                                                 \
          float4 p0 = *(const float4*)&sPR[0 * 68 + cg * 16 + (c4) * 4];  \
          float4 p1 = *(const float4*)&sPR[1 * 68 + cg * 16 + (c4) * 4];  \
          float4 p2 = *(const float4*)&sPR[2 * 68 + cg * 16 + (c4) * 4];  \
          float4 p3 = *(const float4*)&sPR[3 * 68 + cg * 16 + (c4) * 4];  \
          float n0 = fmaf(g0,p0.x, fmaf(g1,p1.x, fmaf(g2,p2.x, g3*p3.x)));\
          float n1 = fmaf(g0,p0.y, fmaf(g1,p1.y, fmaf(g2,p2.y, g3*p3.y)));\
          float n2 = fmaf(g0,p0.z, fmaf(g1,p1.z, fmaf(g2,p2.z, g3*p3.z)));\
          float n3 = fmaf(g0,p0.w, fmaf(g1,p1.w, fmaf(g2,p2.w, g3*p3.w)));\
          if (inblk) { rr[(c4)*4+0]=n0; rr[(c4)*4+1]=n1; rr[(c4)*4+2]=n2; rr[(c4)*4+3]=n3; } \
          else { rr[(c4)*4+0]-=n0; rr[(c4)*4+1]-=n1; rr[(c4)*4+2]-=n2; rr[(c4)*4+3]-=n3; }   \
        }
        CHUNK(0) CHUNK(1) CHUNK(2) CHUNK(3)
#undef CHUNK
        if (cg == (k >> 2)) {
          switch (k & 3) {
            case 0: rr[0] = inblk? g0:-g0; rr[1] = inblk? g1:-g1; rr[2] = inblk? g2:-g2; rr[3] = inblk? g3:-g3; break;
            case 1: rr[4] = inblk? g0:-g0; rr[5] = inblk? g1:-g1; rr[6] = inblk? g2:-g2; rr[7] = inblk? g3:-g3; break;
            case 2: rr[8] = inblk? g0:-g0; rr[9] = inblk? g1:-g1; rr[10]= inblk? g2:-g2; rr[11]= inblk? g3:-g3; break;
            default:rr[12]= inblk? g0:-g0; rr[13]= inblk? g1:-g1; rr[14]= inblk? g2:-g2; rr[15]= inblk? g3:-g3; break;
          }
        }
        __syncthreads();
      }
      {  // write MI (coherent scalars)
#define WMI(j) cst(&MI[i * 64 + cg * 16 + (j)], rr[j]);
        R16(WMI)
#undef WMI
      }
      if (it == TH - 1) {   // kv = MI @ z
        float p2 = 0.f;
#define KV(j) p2 = fmaf(rr[j], Zv[cg * 16 + j], p2);
        R16(KV)
#undef KV
        wred[i * 4 + cg] = p2;
        __syncthreads();
        if (t < 64) cst(&Kv[t], wred[t*4+0] + wred[t*4+1] + wred[t*4+2] + wred[t*4+3]);
      }
    } else {
      float* sWA = scr;   // [256][33]
      for (int q = 0; q < 8; ++q) {
        int idx = q * 256 + t;
        int p = idx >> 3, c4 = (idx & 7) * 4;
        float4 v4 = *(const float4*)(WAg + p * KD + rb + c4);
        sWA[p * 33 + c4 + 0] = v4.x;
        sWA[p * 33 + c4 + 1] = v4.y;
        sWA[p * 33 + c4 + 2] = v4.z;
        sWA[p * 33 + c4 + 3] = v4.w;
      }
      __syncthreads();
      const int c = t & 31, q = t >> 5;    // col c, H rows 4q.., G row m0+q
      float4 hacc = {0.f, 0.f, 0.f, 0.f};
      float gacc = 0.f;
#pragma unroll 8
      for (int p = 0; p < KD; ++p) {
        float wv = sWA[p * 33 + c];
        float4 a4 = *(const float4*)&sA[p * 36 + 4 * q];
        float bq = sBsl[p * 9 + q];
        hacc.x = fmaf(a4.x, wv, hacc.x);
        hacc.y = fmaf(a4.y, wv, hacc.y);
        hacc.z = fmaf(a4.z, wv, hacc.z);
        hacc.w = fmaf(a4.w, wv, hacc.w);
        gacc = fmaf(bq, wv, gacc);
      }
      cst(&Hm[(cb0 + 4*q + 0) * KD + rb + c], hacc.x);
      cst(&Hm[(cb0 + 4*q + 1) * KD + rb + c], hacc.y);
      cst(&Hm[(cb0 + 4*q + 2) * KD + rb + c], hacc.z);
      cst(&Hm[(cb0 + 4*q + 3) * KD + rb + c], hacc.w);
      cst(&Gm[(m0 + q) * KD + rb + c], gacc);
    }
    gbar(flags, ++ep);

    // =========== PhC: K strip, V' tile, v' ===========
    if (w >= 1) {
      float* sMI_ = scr;                 // [64][65]
      float* sGb  = scr + 4160;          // [64][36]  G[:, cb2 strip]
      float* sGc  = scr + 6464;          // [64][36]  G[:, rb2 strip]
      float* sKs  = scr + 8768;          // [64][33]
      const int cb2 = rb, rb2 = cb0;
      for (int q = 0; q < 16; ++q) { int idx = q * 256 + t; int row = idx >> 6, col = idx & 63; sMI_[row * 65 + col] = MI[idx]; }
      for (int q = 0; q < 2; ++q) {
        int idx = q * 256 + t; int m = idx >> 3, c4 = (idx & 7) * 4;
        float4 g4 = *(const float4*)(Gm + m * KD + cb2 + c4);
        sGb[m * 36 + c4 + 0] = g4.x; sGb[m * 36 + c4 + 1] = g4.y;
        sGb[m * 36 + c4 + 2] = g4.z; sGb[m * 36 + c4 + 3] = g4.w;
      }
      for (int q = 0; q < 2; ++q) {
        int idx = q * 256 + t; int m = idx >> 3, c4 = (idx & 7) * 4;
        float4 g4 = *(const float4*)(Gm + m * KD + rb2 + c4);
        sGc[m * 36 + c4 + 0] = g4.x; sGc[m * 36 + c4 + 1] = g4.y;
        sGc[m * 36 + c4 + 2] = g4.z; sGc[m * 36 + c4 + 3] = g4.w;
      }
      if (t < 64) sZ[t] = Zv[t];
      __syncthreads();
      {  // K[m][cb2 strip]: thread (m = t&63, wv = t>>6) -> 8 cols
        const int m = t & 63, wv = t >> 6;
        float k0=0,k1=0,k2=0,k3=0,k4=0,k5=0,k6=0,k7=0;
#pragma unroll 4
        for (int p = 0; p < UD; ++p) {
          float mi = sMI_[m * 65 + p];
          float4 ga = *(const float4*)&sGb[p * 36 + wv * 8 + 0];
          float4 gb2 = *(const float4*)&sGb[p * 36 + wv * 8 + 4];
          k0 = fmaf(mi, ga.x, k0); k1 = fmaf(mi, ga.y, k1);
          k2 = fmaf(mi, ga.z, k2); k3 = fmaf(mi, ga.w, k3);
          k4 = fmaf(mi, gb2.x, k4); k5 = fmaf(mi, gb2.y, k5);
          k6 = fmaf(mi, gb2.z, k6); k7 = fmaf(mi, gb2.w, k7);
        }
        sKs[m * 33 + wv * 8 + 0] = k0; sKs[m * 33 + wv * 8 + 1] = k1;
        sKs[m * 33 + wv * 8 + 2] = k2; sKs[m * 33 + wv * 8 + 3] = k3;
        sKs[m * 33 + wv * 8 + 4] = k4; sKs[m * 33 + wv * 8 + 5] = k5;
        sKs[m * 33 + wv * 8 + 6] = k6; sKs[m * 33 + wv * 8 + 7] = k7;
        if (it == TH - 1 && hb == 0) {
          cst(&K0[m * KD + cb2 + wv * 8 + 0], k0); cst(&K0[m * KD + cb2 + wv * 8 + 1], k1);
          cst(&K0[m * KD + cb2 + wv * 8 + 2], k2); cst(&K0[m * KD + cb2 + wv * 8 + 3], k3);
          cst(&K0[m * KD + cb2 + wv * 8 + 4], k4); cst(&K0[m * KD + cb2 + wv * 8 + 5], k5);
          cst(&K0[m * KD + cb2 + wv * 8 + 6], k6); cst(&K0[m * KD + cb2 + wv * 8 + 7], k7);
        }
      }
      __syncthreads();
      {  // V' tile: rows rb2+4q.., col cb2+c
        const int c = t & 31, q = t >> 5;
        float a0 = 0.f, a1 = 0.f, a2 = 0.f, a3 = 0.f;
#pragma unroll 8
        for (int m = 0; m < UD; ++m) {
          float4 g4 = *(const float4*)&sGc[m * 36 + 4 * q];
          float km = sKs[m * 33 + c];
          a0 = fmaf(g4.x, km, a0); a1 = fmaf(g4.y, km, a1);
          a2 = fmaf(g4.z, km, a2); a3 = fmaf(g4.w, km, a3);
        }
        const int cc = cb2 + c;
        int r = rb2 + 4 * q;
        float h0 = Hm[(r+0) * KD + cc], h1 = Hm[(r+1) * KD + cc];
        float h2 = Hm[(r+2) * KD + cc], h3 = Hm[(r+3) * KD + cc];
        cst(&V[(r+0) * KD + cc], h0 - a0 + ((r+0 == cc) ? sQd[4*q+0] : 0.f));
        cst(&V[(r+1) * KD + cc], h1 - a1 + ((r+1 == cc) ? sQd[4*q+1] : 0.f));
        cst(&V[(r+2) * KD + cc], h2 - a2 + ((r+2 == cc) ? sQd[4*q+2] : 0.f));
        cst(&V[(r+3) * KD + cc], h3 - a3 + ((r+3 == cc) ? sQd[4*q+3] : 0.f));
      }
      if (hb == 0) {     // v' slice
        int c = t & 31, part = t >> 5;
        float acc2 = 0.f;
#pragma unroll
        for (int m = part * 8; m < part * 8 + 8; ++m) acc2 = fmaf(sKs[m * 33 + c], sZ[m], acc2);
        sRed[part * 36 + c] = acc2;
        __syncthreads();
        if (t < 32) {
          float s2 = 0.f;
#pragma unroll
          for (int pt = 0; pt < 8; ++pt) s2 += sRed[pt * 36 + t];
          cst(&vv[cb2 + t], Atv[cb2 + t] - s2 + Qg[cb2 + t]);
        }
      }
    }
    gbar(flags, ++ep);
  }

  // ---------- final: NKT = -(K0 @ W)^T, Cv = kv - K0 @ b ----------
  if (w >= 1 && t < 128) {
    int j = t & 63, kk = 2 * u + (t >> 6);
    float acc = 0.f;
#pragma unroll 8
    for (int i = 0; i < KD; ++i) acc = fmaf(K0[j * KD + i], W[i * XD + kk], acc);
    cst(&NKT[kk * UD + j], -acc);
  }
  if (w == 0 && t < UD) {
    float acc = 0.f;
#pragma unroll 8
    for (int i = 0; i < KD; ++i) acc = fmaf(K0[t * KD + i], bphi[i], acc);
    cst(&Cv[t], Kv[t] - acc);
  }
}

__global__ __launch_bounds__(256) void k_batch(const float* __restrict__ x0,
                                               const float* __restrict__ ws,
                                               float* __restrict__ out)
{
  __shared__ float kt[XD][UD];
  __shared__ float cvs[UD];
  const int t = threadIdx.x;
  {
    const float4* src = (const float4*)(ws + OFF_NKT);
    float4* dst = (float4*)kt;
#pragma unroll
    for (int idx = 0; idx < (XD * UD / 4) / 256; ++idx)
      dst[t + idx * 256] = src[t + idx * 256];
  }
  if (t < UD) cvs[t] = ws[OFF_CV + t];
  __syncthreads();

  const int ty = t >> 4, tx = t & 15;
  const long r0 = (long)blockIdx.x * 64 + ty * 4;
  const float* xp = x0 + r0 * XD;

#define FMA4(acc, s, f4)                      \
  acc.x = fmaf((s), (f4).x, acc.x);           \
  acc.y = fmaf((s), (f4).y, acc.y);           \
  acc.z = fmaf((s), (f4).z, acc.z);           \
  acc.w = fmaf((s), (f4).w, acc.w);

  float4 acc0 = {0,0,0,0}, acc1 = {0,0,0,0}, acc2 = {0,0,0,0}, acc3 = {0,0,0,0};
#pragma unroll 2
  for (int k = 0; k < XD; k += 4) {
    float4 x_0 = *(const float4*)(xp + 0 * XD + k);
    float4 x_1 = *(const float4*)(xp + 1 * XD + k);
    float4 x_2 = *(const float4*)(xp + 2 * XD + k);
    float4 x_3 = *(const float4*)(xp + 3 * XD + k);
    float4 k_0 = *(const float4*)&kt[k + 0][tx * 4];
    float4 k_1 = *(const float4*)&kt[k + 1][tx * 4];
    float4 k_2 = *(const float4*)&kt[k + 2][tx * 4];
    float4 k_3 = *(const float4*)&kt[k + 3][tx * 4];
    FMA4(acc0, x_0.x, k_0) FMA4(acc0, x_0.y, k_1) FMA4(acc0, x_0.z, k_2) FMA4(acc0, x_0.w, k_3)
    FMA4(acc1, x_1.x, k_0) FMA4(acc1, x_1.y, k_1) FMA4(acc1, x_1.z, k_2) FMA4(acc1, x_1.w, k_3)
    FMA4(acc2, x_2.x, k_0) FMA4(acc2, x_2.y, k_1) FMA4(acc2, x_2.z, k_2) FMA4(acc2, x_2.w, k_3)
    FMA4(acc3, x_3.x, k_0) FMA4(acc3, x_3.y, k_1) FMA4(acc3, x_3.z, k_2) FMA4(acc3, x_3.w, k_3)
  }
  float4 cq = *(float4*)&cvs[tx * 4];
  acc0.x += cq.x; acc0.y += cq.y; acc0.z += cq.z; acc0.w += cq.w;
  acc1.x += cq.x; acc1.y += cq.y; acc1.z += cq.z; acc1.w += cq.w;
  acc2.x += cq.x; acc2.y += cq.y; acc2.z += cq.z; acc2.w += cq.w;
  acc3.x += cq.x; acc3.y += cq.y; acc3.z += cq.z; acc3.w += cq.w;
  *(float4*)(out + (r0 + 0) * UD + tx * 4) = acc0;
  *(float4*)(out + (r0 + 1) * UD + tx * 4) = acc1;
  *(float4*)(out + (r0 + 2) * UD + tx * 4) = acc2;
  *(float4*)(out + (r0 + 3) * UD + tx * 4) = acc3;
}

extern "C" void kernel_launch(void* const* d_in, const int* in_sizes, int n_in,
                              void* d_out, int out_size, void* d_ws, size_t ws_size,
                              hipStream_t stream) {
  const float* x0   = (const float*)d_in[0];
  const float* W    = (const float*)d_in[1];
  const float* bphi = (const float*)d_in[2];
  const float* xg   = (const float*)d_in[3];
  const float* A    = (const float*)d_in[4];
  const float* B    = (const float*)d_in[5];
  const float* ql   = (const float*)d_in[6];
  const float* rl   = (const float*)d_in[7];
  float* ws  = (float*)d_ws;
  float* out = (float*)d_out;

  hipLaunchKernelGGL(k_zero, dim3(1), dim3(256), 0, stream, ws);
  hipLaunchKernelGGL(k_ric, dim3(NWG), dim3(256), 0, stream,
                     A, B, W, bphi, xg, ql, rl, ws);
  int rows = in_sizes[0] / XD;
  int nblk = rows / 64;
  hipLaunchKernelGGL(k_batch, dim3(nblk), dim3(256), 0, stream, x0, ws, out);
}

// Round 6
// 9430.746 us; speedup vs baseline: 1.3803x; 1.3803x over previous
//
#include <hip/hip_runtime.h>
#include <math.h>

#define KD 256
#define UD 64
#define XD 128
#define TH 200

// ws float offsets
#define OFF_V     0        // 65536
#define OFF_WA    65536    // 65536  WA = V@A
#define OFF_H     131072   // 65536  H = At@WA
#define OFF_G     196608   // 16384  G = Bt@WA (64x256)
#define OFF_K0    212992   // 16384
#define OFF_MI    229376   // 4096   M^-1
#define OFF_MP    233472   // 8*4096 M partials
#define OFF_v     266240
#define OFF_ATV   266496
#define OFF_Z     266752
#define OFF_QG    266816
#define OFF_QD    267072
#define OFF_RD    267328
#define OFF_KV    267392
#define OFF_CV    267456
#define OFF_NKT   267520   // 8192

// in-place 4x4 inverse, unpivoted GJ (principal block of SPD matrix)
__device__ __forceinline__ void inv4(float* D) {
#pragma unroll
  for (int p = 0; p < 4; ++p) {
    float ip = 1.0f / D[p * 4 + p];
#pragma unroll
    for (int i2 = 0; i2 < 4; ++i2)
      if (i2 != p) {
        float f = D[i2 * 4 + p] * ip;
#pragma unroll
        for (int j = 0; j < 4; ++j)
          if (j != p) D[i2 * 4 + j] -= f * D[p * 4 + j];
        D[i2 * 4 + p] = -f;
      }
#pragma unroll
    for (int j = 0; j < 4; ++j)
      if (j != p) D[p * 4 + j] *= ip;
    D[p * 4 + p] = ip;
  }
}

#define R16(OP) OP(0) OP(1) OP(2) OP(3) OP(4) OP(5) OP(6) OP(7) OP(8) OP(9) OP(10) OP(11) OP(12) OP(13) OP(14) OP(15)

// ================= init =================
__global__ __launch_bounds__(256) void k_init(
    const float* __restrict__ W, const float* __restrict__ bphi,
    const float* __restrict__ xg, const float* __restrict__ qlog,
    const float* __restrict__ rlog, float* __restrict__ ws)
{
  const int w = blockIdx.x, t = threadIdx.x;
  float* V = ws + OFF_V;
  for (int rr2 = 0; rr2 < 4; ++rr2) {
    int r = 4 * w + rr2;
    V[r * KD + t] = (r == t) ? expf(qlog[r]) : 0.f;
  }
  if (w < 4 && t < 64) {
    int i = w * 64 + t;
    float acc = 0.f;
    for (int p = 0; p < XD; ++p) acc = fmaf(W[i * XD + p], xg[p], acc);
    float g = acc + bphi[i];
    float qd = expf(qlog[i]);
    ws[OFF_QD + i] = qd; ws[OFF_QG + i] = qd * g; ws[OFF_v + i] = qd * g;
  }
  if (w == 4 && t < UD) ws[OFF_RD + t] = expf(rlog[t]);
}

// ================= phase 1: WA = V@A tile, VB, M-partials, Atv, z =================
__global__ __launch_bounds__(256) void k_ph1(
    const float* __restrict__ A, const float* __restrict__ B,
    float* __restrict__ ws)
{
  const int u = blockIdx.x, t = threadIdx.x;
  const int sb = u & 7, hb = u >> 3;
  const int rb = sb * 32, cb0 = hb * 32, m0 = hb * 8;
  float* V   = ws + OFF_V;
  float* WAg = ws + OFF_WA;

  __shared__ float sVt[256 * 36];   // V[p][rb+r] (row-major; V symmetric)
  __shared__ float sA [256 * 36];   // A[p][cb0+r]
  __shared__ float sBsl[256 * 8];   // B[p][m0+j]
  __shared__ float sBr[32 * 64];    // B[rb+r][a]
  __shared__ float svv[256];
  __shared__ float sVB[32 * 9];
  __shared__ float sRed[8 * 36];

  // ---- stage (all float4, high MLP) ----
  for (int q = 0; q < 8; ++q) {
    int idx = q * 256 + t; int p = idx >> 3, r4 = (idx & 7) * 4;
    *(float4*)&sVt[p * 36 + r4] = *(const float4*)(V + p * KD + rb + r4);
  }
  for (int q = 0; q < 8; ++q) {
    int idx = q * 256 + t; int p = idx >> 3, r4 = (idx & 7) * 4;
    *(float4*)&sA[p * 36 + r4] = *(const float4*)(A + p * KD + cb0 + r4);
  }
  for (int q = 0; q < 2; ++q) {
    int idx = q * 256 + t; int p = idx >> 1, j4 = (idx & 1) * 4;
    *(float4*)&sBsl[p * 8 + j4] = *(const float4*)(B + p * UD + m0 + j4);
  }
  for (int q = 0; q < 2; ++q) {
    int idx = q * 256 + t; int r = idx >> 4, a4 = (idx & 15) * 4;
    *(float4*)&sBr[r * 64 + a4] = *(const float4*)(B + (rb + r) * UD + a4);
  }
  svv[t] = ws[OFF_v + t];
  __syncthreads();

  const int j = t & 31, rq = t >> 5;
  float4 acc = {0.f, 0.f, 0.f, 0.f};
  float avb0 = 0.f, avb1 = 0.f, avb2 = 0.f, avb3 = 0.f;
  const bool dovb = (j < 8);
#pragma unroll 8
  for (int p = 0; p < KD; ++p) {
    float4 v4 = *(const float4*)&sVt[p * 36 + rq * 4];
    float a = sA[p * 36 + j];
    acc.x = fmaf(v4.x, a, acc.x);
    acc.y = fmaf(v4.y, a, acc.y);
    acc.z = fmaf(v4.z, a, acc.z);
    acc.w = fmaf(v4.w, a, acc.w);
    if (dovb) {
      float b = sBsl[p * 8 + j];
      avb0 = fmaf(v4.x, b, avb0);
      avb1 = fmaf(v4.y, b, avb1);
      avb2 = fmaf(v4.z, b, avb2);
      avb3 = fmaf(v4.w, b, avb3);
    }
  }
  WAg[(rb + 4 * rq + 0) * KD + cb0 + j] = acc.x;
  WAg[(rb + 4 * rq + 1) * KD + cb0 + j] = acc.y;
  WAg[(rb + 4 * rq + 2) * KD + cb0 + j] = acc.z;
  WAg[(rb + 4 * rq + 3) * KD + cb0 + j] = acc.w;
  if (dovb) {
    sVB[(4 * rq + 0) * 9 + j] = avb0;
    sVB[(4 * rq + 1) * 9 + j] = avb1;
    sVB[(4 * rq + 2) * 9 + j] = avb2;
    sVB[(4 * rq + 3) * 9 + j] = avb3;
  }
  if (sb == 0) {                     // Atv partials
    int c = t & 31, part = t >> 5;
    float acc2 = 0.f;
#pragma unroll 8
    for (int p = part * 32; p < part * 32 + 32; ++p) acc2 = fmaf(sA[p * 36 + c], svv[p], acc2);
    sRed[part * 36 + c] = acc2;
  }
  if (sb == 1 && t < 64) {           // z partials
    int jz = t & 7, part = t >> 3;
    float acc2 = 0.f;
#pragma unroll 8
    for (int p = part * 32; p < part * 32 + 32; ++p) acc2 = fmaf(sBsl[p * 8 + jz], svv[p], acc2);
    sRed[part * 36 + jz] = acc2;
  }
  __syncthreads();
  {  // M-partial: Mp[a][m0+j] = sum_r Br[r][a]*VB[r][j]
    int a = t & 63, j2 = (t >> 6) * 2;
    float mp0 = 0.f, mp1 = 0.f;
#pragma unroll 8
    for (int r = 0; r < 32; ++r) {
      float bv = sBr[r * 64 + a];
      mp0 = fmaf(bv, sVB[r * 9 + j2 + 0], mp0);
      mp1 = fmaf(bv, sVB[r * 9 + j2 + 1], mp1);
    }
    ws[OFF_MP + sb * 4096 + a * 64 + m0 + j2 + 0] = mp0;
    ws[OFF_MP + sb * 4096 + a * 64 + m0 + j2 + 1] = mp1;
  }
  if (sb == 0 && t < 32) {
    float a2 = 0.f;
#pragma unroll
    for (int pt = 0; pt < 8; ++pt) a2 += sRed[pt * 36 + t];
    ws[OFF_ATV + cb0 + t] = a2;
  }
  if (sb == 1 && t < 8) {
    float a2 = 0.f;
#pragma unroll
    for (int pt = 0; pt < 8; ++pt) a2 += sRed[pt * 36 + t];
    ws[OFF_Z + m0 + t] = a2;
  }
}

// ================= phase 2: WG0 -> MI = M^-1; workers -> H, G =================
__global__ __launch_bounds__(256) void k_ph2(
    const float* __restrict__ A, const float* __restrict__ B,
    float* __restrict__ ws, int last)
{
  const int w = blockIdx.x, t = threadIdx.x;
  const int u = w - 1;
  float* WAg = ws + OFF_WA;
  float* MI  = ws + OFF_MI;

  __shared__ float sWA[256 * 33];
  __shared__ float sA [256 * 36];
  __shared__ float sBsl[256 * 8];
  __shared__ float scr[608];        // WG0: sPR[4][68] + sF[64][5] (union w/ worker LDS unused)
  __shared__ float wred[256];

  if (w == 0) {
    float* sPR = scr;            // [4][68]
    float* sF  = scr + 280;      // [64][5]
    const int i = t & 63, cg = t >> 6;
    const float rdi = ws[OFF_RD + i];
    float rr[16];
    {
      float4 s0 = {0,0,0,0}, s1 = {0,0,0,0}, s2 = {0,0,0,0}, s3 = {0,0,0,0};
#pragma unroll
      for (int sb2 = 0; sb2 < 8; ++sb2) {
        const float* mp = ws + OFF_MP + sb2 * 4096 + i * 64 + cg * 16;
        float4 a0 = *(const float4*)(mp + 0);
        float4 a1 = *(const float4*)(mp + 4);
        float4 a2 = *(const float4*)(mp + 8);
        float4 a3 = *(const float4*)(mp + 12);
        s0.x += a0.x; s0.y += a0.y; s0.z += a0.z; s0.w += a0.w;
        s1.x += a1.x; s1.y += a1.y; s1.z += a1.z; s1.w += a1.w;
        s2.x += a2.x; s2.y += a2.y; s2.z += a2.z; s2.w += a2.w;
        s3.x += a3.x; s3.y += a3.y; s3.z += a3.z; s3.w += a3.w;
      }
      rr[0]=s0.x; rr[1]=s0.y; rr[2]=s0.z; rr[3]=s0.w;
      rr[4]=s1.x; rr[5]=s1.y; rr[6]=s1.z; rr[7]=s1.w;
      rr[8]=s2.x; rr[9]=s2.y; rr[10]=s2.z; rr[11]=s2.w;
      rr[12]=s3.x; rr[13]=s3.y; rr[14]=s3.z; rr[15]=s3.w;
#define DIAG(j) rr[j] += (cg * 16 + j == i) ? rdi : 0.f;
      R16(DIAG)
#undef DIAG
    }
    for (int k = 0; k < 16; ++k) {
      const int prw = i - 4 * k;
      const bool inblk = (unsigned)prw < 4u;
      if (inblk) {
#define ST(j) sPR[prw * 68 + cg * 16 + j] = rr[j];
        R16(ST)
#undef ST
      }
      if (cg == (k >> 2)) {
        switch (k & 3) {
          case 0: sF[i*5+0]=rr[0];  sF[i*5+1]=rr[1];  sF[i*5+2]=rr[2];  sF[i*5+3]=rr[3];  break;
          case 1: sF[i*5+0]=rr[4];  sF[i*5+1]=rr[5];  sF[i*5+2]=rr[6];  sF[i*5+3]=rr[7];  break;
          case 2: sF[i*5+0]=rr[8];  sF[i*5+1]=rr[9];  sF[i*5+2]=rr[10]; sF[i*5+3]=rr[11]; break;
          default:sF[i*5+0]=rr[12]; sF[i*5+1]=rr[13]; sF[i*5+2]=rr[14]; sF[i*5+3]=rr[15]; break;
        }
      }
      __syncthreads();
      float D[16];
#pragma unroll
      for (int q = 0; q < 4; ++q) {
        D[q*4+0] = sPR[q*68 + 4*k + 0];
        D[q*4+1] = sPR[q*68 + 4*k + 1];
        D[q*4+2] = sPR[q*68 + 4*k + 2];
        D[q*4+3] = sPR[q*68 + 4*k + 3];
      }
      inv4(D);
      float f0 = sF[i*5+0], f1 = sF[i*5+1], f2 = sF[i*5+2], f3 = sF[i*5+3];
      float g0, g1, g2, g3;
      if (inblk) {
        g0 = prw==0?D[0]:prw==1?D[4]:prw==2?D[8]:D[12];
        g1 = prw==0?D[1]:prw==1?D[5]:prw==2?D[9]:D[13];
        g2 = prw==0?D[2]:prw==1?D[6]:prw==2?D[10]:D[14];
        g3 = prw==0?D[3]:prw==1?D[7]:prw==2?D[11]:D[15];
      } else {
        g0 = f0*D[0] + f1*D[4] + f2*D[8]  + f3*D[12];
        g1 = f0*D[1] + f1*D[5] + f2*D[9]  + f3*D[13];
        g2 = f0*D[2] + f1*D[6] + f2*D[10] + f3*D[14];
        g3 = f0*D[3] + f1*D[7] + f2*D[11] + f3*D[15];
      }
#define CHUNK(c4)                                                         \
      {                                                                   \
        float4 p0 = *(const float4*)&sPR[0 * 68 + cg * 16 + (c4) * 4];    \
        float4 p1 = *(const float4*)&sPR[1 * 68 + cg * 16 + (c4) * 4];    \
        float4 p2 = *(const float4*)&sPR[2 * 68 + cg * 16 + (c4) * 4];    \
        float4 p3 = *(const float4*)&sPR[3 * 68 + cg * 16 + (c4) * 4];    \
        float n0 = fmaf(g0,p0.x, fmaf(g1,p1.x, fmaf(g2,p2.x, g3*p3.x)));  \
        float n1 = fmaf(g0,p0.y, fmaf(g1,p1.y, fmaf(g2,p2.y, g3*p3.y)));  \
        float n2 = fmaf(g0,p0.z, fmaf(g1,p1.z, fmaf(g2,p2.z, g3*p3.z)));  \
        float n3 = fmaf(g0,p0.w, fmaf(g1,p1.w, fmaf(g2,p2.w, g3*p3.w)));  \
        if (inblk) { rr[(c4)*4+0]=n0; rr[(c4)*4+1]=n1; rr[(c4)*4+2]=n2; rr[(c4)*4+3]=n3; } \
        else { rr[(c4)*4+0]-=n0; rr[(c4)*4+1]-=n1; rr[(c4)*4+2]-=n2; rr[(c4)*4+3]-=n3; }   \
      }
      CHUNK(0) CHUNK(1) CHUNK(2) CHUNK(3)
#undef CHUNK
      if (cg == (k >> 2)) {
        switch (k & 3) {
          case 0: rr[0] = inblk? g0:-g0; rr[1] = inblk? g1:-g1; rr[2] = inblk? g2:-g2; rr[3] = inblk? g3:-g3; break;
          case 1: rr[4] = inblk? g0:-g0; rr[5] = inblk? g1:-g1; rr[6] = inblk? g2:-g2; rr[7] = inblk? g3:-g3; break;
          case 2: rr[8] = inblk? g0:-g0; rr[9] = inblk? g1:-g1; rr[10]= inblk? g2:-g2; rr[11]= inblk? g3:-g3; break;
          default:rr[12]= inblk? g0:-g0; rr[13]= inblk? g1:-g1; rr[14]= inblk? g2:-g2; rr[15]= inblk? g3:-g3; break;
        }
      }
      __syncthreads();
    }
    *(float4*)(MI + i * 64 + cg * 16 + 0)  = *(float4*)&rr[0];
    *(float4*)(MI + i * 64 + cg * 16 + 4)  = *(float4*)&rr[4];
    *(float4*)(MI + i * 64 + cg * 16 + 8)  = *(float4*)&rr[8];
    *(float4*)(MI + i * 64 + cg * 16 + 12) = *(float4*)&rr[12];
    if (last) {   // kv = MI @ z
      float p2 = 0.f;
#define KV(j) p2 = fmaf(rr[j], ws[OFF_Z + cg * 16 + j], p2);
      R16(KV)
#undef KV
      wred[i * 4 + cg] = p2;
      __syncthreads();
      if (t < 64) ws[OFF_KV + t] = wred[t*4+0] + wred[t*4+1] + wred[t*4+2] + wred[t*4+3];
    }
  } else {
    const int sb = u & 7, hb = u >> 3;
    const int rb = sb * 32, cb0 = hb * 32, m0 = hb * 8;
    for (int q = 0; q < 8; ++q) {
      int idx = q * 256 + t;
      int p = idx >> 3, c4 = (idx & 7) * 4;
      float4 v4 = *(const float4*)(WAg + p * KD + rb + c4);
      sWA[p * 33 + c4 + 0] = v4.x;
      sWA[p * 33 + c4 + 1] = v4.y;
      sWA[p * 33 + c4 + 2] = v4.z;
      sWA[p * 33 + c4 + 3] = v4.w;
    }
    for (int q = 0; q < 8; ++q) {
      int idx = q * 256 + t; int p = idx >> 3, r4 = (idx & 7) * 4;
      *(float4*)&sA[p * 36 + r4] = *(const float4*)(A + p * KD + cb0 + r4);
    }
    for (int q = 0; q < 2; ++q) {
      int idx = q * 256 + t; int p = idx >> 1, j4 = (idx & 1) * 4;
      *(float4*)&sBsl[p * 8 + j4] = *(const float4*)(B + p * UD + m0 + j4);
    }
    __syncthreads();
    const int c = t & 31, q = t >> 5;    // col c, H rows 4q.., G row m0+q
    float4 hacc = {0.f, 0.f, 0.f, 0.f};
    float gacc = 0.f;
#pragma unroll 8
    for (int p = 0; p < KD; ++p) {
      float wv = sWA[p * 33 + c];
      float4 a4 = *(const float4*)&sA[p * 36 + 4 * q];
      float bq = sBsl[p * 8 + q];
      hacc.x = fmaf(a4.x, wv, hacc.x);
      hacc.y = fmaf(a4.y, wv, hacc.y);
      hacc.z = fmaf(a4.z, wv, hacc.z);
      hacc.w = fmaf(a4.w, wv, hacc.w);
      gacc = fmaf(bq, wv, gacc);
    }
    float* Hm = ws + OFF_H;
    float* Gm = ws + OFF_G;
    Hm[(cb0 + 4*q + 0) * KD + rb + c] = hacc.x;
    Hm[(cb0 + 4*q + 1) * KD + rb + c] = hacc.y;
    Hm[(cb0 + 4*q + 2) * KD + rb + c] = hacc.z;
    Hm[(cb0 + 4*q + 3) * KD + rb + c] = hacc.w;
    Gm[(m0 + q) * KD + rb + c] = gacc;
  }
}

// ================= phase 3: K strip, V' tile, v' =================
__global__ __launch_bounds__(256) void k_ph3(float* __restrict__ ws, int last)
{
  const int u = blockIdx.x, t = threadIdx.x;
  const int sb = u & 7, hb = u >> 3;
  const int cb2 = sb * 32, rb2 = hb * 32;
  float* V  = ws + OFF_V;
  float* Hm = ws + OFF_H;
  float* Gm = ws + OFF_G;

  __shared__ float sMI_[64 * 65];
  __shared__ float sGb [64 * 36];
  __shared__ float sGc [64 * 36];
  __shared__ float sKs [64 * 33];
  __shared__ float sZ[64];
  __shared__ float sQd[32];
  __shared__ float sRed[8 * 36];

  for (int q = 0; q < 16; ++q) { int idx = q * 256 + t; int row = idx >> 6, col = idx & 63; sMI_[row * 65 + col] = ws[OFF_MI + idx]; }
  for (int q = 0; q < 2; ++q) {
    int idx = q * 256 + t; int m = idx >> 3, c4 = (idx & 7) * 4;
    float4 g4 = *(const float4*)(Gm + m * KD + cb2 + c4);
    sGb[m * 36 + c4 + 0] = g4.x; sGb[m * 36 + c4 + 1] = g4.y;
    sGb[m * 36 + c4 + 2] = g4.z; sGb[m * 36 + c4 + 3] = g4.w;
  }
  for (int q = 0; q < 2; ++q) {
    int idx = q * 256 + t; int m = idx >> 3, c4 = (idx & 7) * 4;
    float4 g4 = *(const float4*)(Gm + m * KD + rb2 + c4);
    sGc[m * 36 + c4 + 0] = g4.x; sGc[m * 36 + c4 + 1] = g4.y;
    sGc[m * 36 + c4 + 2] = g4.z; sGc[m * 36 + c4 + 3] = g4.w;
  }
  if (t < 64) sZ[t] = ws[OFF_Z + t];
  if (t < 32) sQd[t] = ws[OFF_QD + rb2 + t];
  __syncthreads();
  {  // K[m][cb2 strip]
    const int m = t & 63, wv = t >> 6;
    float k0=0,k1=0,k2=0,k3=0,k4=0,k5=0,k6=0,k7=0;
#pragma unroll 4
    for (int p = 0; p < UD; ++p) {
      float mi = sMI_[m * 65 + p];
      float4 ga  = *(const float4*)&sGb[p * 36 + wv * 8 + 0];
      float4 gb2 = *(const float4*)&sGb[p * 36 + wv * 8 + 4];
      k0 = fmaf(mi, ga.x, k0); k1 = fmaf(mi, ga.y, k1);
      k2 = fmaf(mi, ga.z, k2); k3 = fmaf(mi, ga.w, k3);
      k4 = fmaf(mi, gb2.x, k4); k5 = fmaf(mi, gb2.y, k5);
      k6 = fmaf(mi, gb2.z, k6); k7 = fmaf(mi, gb2.w, k7);
    }
    sKs[m * 33 + wv * 8 + 0] = k0; sKs[m * 33 + wv * 8 + 1] = k1;
    sKs[m * 33 + wv * 8 + 2] = k2; sKs[m * 33 + wv * 8 + 3] = k3;
    sKs[m * 33 + wv * 8 + 4] = k4; sKs[m * 33 + wv * 8 + 5] = k5;
    sKs[m * 33 + wv * 8 + 6] = k6; sKs[m * 33 + wv * 8 + 7] = k7;
    if (last && hb == 0) {
      float* K0 = ws + OFF_K0;
      K0[m * KD + cb2 + wv * 8 + 0] = k0; K0[m * KD + cb2 + wv * 8 + 1] = k1;
      K0[m * KD + cb2 + wv * 8 + 2] = k2; K0[m * KD + cb2 + wv * 8 + 3] = k3;
      K0[m * KD + cb2 + wv * 8 + 4] = k4; K0[m * KD + cb2 + wv * 8 + 5] = k5;
      K0[m * KD + cb2 + wv * 8 + 6] = k6; K0[m * KD + cb2 + wv * 8 + 7] = k7;
    }
  }
  __syncthreads();
  {  // V' tile: rows rb2+4q.., col cb2+c
    const int c = t & 31, q = t >> 5;
    float a0 = 0.f, a1 = 0.f, a2 = 0.f, a3 = 0.f;
#pragma unroll 8
    for (int m = 0; m < UD; ++m) {
      float4 g4 = *(const float4*)&sGc[m * 36 + 4 * q];
      float km = sKs[m * 33 + c];
      a0 = fmaf(g4.x, km, a0); a1 = fmaf(g4.y, km, a1);
      a2 = fmaf(g4.z, km, a2); a3 = fmaf(g4.w, km, a3);
    }
    const int cc = cb2 + c;
    int r = rb2 + 4 * q;
    float h0 = Hm[(r+0) * KD + cc], h1 = Hm[(r+1) * KD + cc];
    float h2 = Hm[(r+2) * KD + cc], h3 = Hm[(r+3) * KD + cc];
    V[(r+0) * KD + cc] = h0 - a0 + ((r+0 == cc) ? sQd[4*q+0] : 0.f);
    V[(r+1) * KD + cc] = h1 - a1 + ((r+1 == cc) ? sQd[4*q+1] : 0.f);
    V[(r+2) * KD + cc] = h2 - a2 + ((r+2 == cc) ? sQd[4*q+2] : 0.f);
    V[(r+3) * KD + cc] = h3 - a3 + ((r+3 == cc) ? sQd[4*q+3] : 0.f);
  }
  if (hb == 0) {     // v' slice
    int c = t & 31, part = t >> 5;
    float acc2 = 0.f;
#pragma unroll
    for (int m = part * 8; m < part * 8 + 8; ++m) acc2 = fmaf(sKs[m * 33 + c], sZ[m], acc2);
    sRed[part * 36 + c] = acc2;
    __syncthreads();
    if (t < 32)  {
      float s2 = 0.f;
#pragma unroll
      for (int pt = 0; pt < 8; ++pt) s2 += sRed[pt * 36 + t];
      ws[OFF_v + cb2 + t] = ws[OFF_ATV + cb2 + t] - s2 + ws[OFF_QG + cb2 + t];
    }
  }
}

// ================= final: NKT = -(K0@W)^T, Cv = kv - K0@b =================
__global__ __launch_bounds__(256) void k_fin(
    const float* __restrict__ W, const float* __restrict__ bphi,
    float* __restrict__ ws)
{
  const int w = blockIdx.x, t = threadIdx.x;
  const float* K0 = ws + OFF_K0;
  if (w >= 1 && t < 128) {
    int j = t & 63, kk = 2 * (w - 1) + (t >> 6);
    float acc = 0.f;
#pragma unroll 8
    for (int i = 0; i < KD; ++i) acc = fmaf(K0[j * KD + i], W[i * XD + kk], acc);
    ws[OFF_NKT + kk * UD + j] = -acc;
  }
  if (w == 0 && t < UD) {
    float acc = 0.f;
#pragma unroll 8
    for (int i = 0; i < KD; ++i) acc = fmaf(K0[t * KD + i], bphi[i], acc);
    ws[OFF_CV + t] = ws[OFF_KV + t] - acc;
  }
}

__global__ __launch_bounds__(256) void k_batch(const float* __restrict__ x0,
                                               const float* __restrict__ ws,
                                               float* __restrict__ out)
{
  __shared__ float kt[XD][UD];
  __shared__ float cvs[UD];
  const int t = threadIdx.x;
  {
    const float4* src = (const float4*)(ws + OFF_NKT);
    float4* dst = (float4*)kt;
#pragma unroll
    for (int idx = 0; idx < (XD * UD / 4) / 256; ++idx)
      dst[t + idx * 256] = src[t + idx * 256];
  }
  if (t < UD) cvs[t] = ws[OFF_CV + t];
  __syncthreads();

  const int ty = t >> 4, tx = t & 15;
  const long r0 = (long)blockIdx.x * 64 + ty * 4;
  const float* xp = x0 + r0 * XD;

#define FMA4(acc, s, f4)                      \
  acc.x = fmaf((s), (f4).x, acc.x);           \
  acc.y = fmaf((s), (f4).y, acc.y);           \
  acc.z = fmaf((s), (f4).z, acc.z);           \
  acc.w = fmaf((s), (f4).w, acc.w);

  float4 acc0 = {0,0,0,0}, acc1 = {0,0,0,0}, acc2 = {0,0,0,0}, acc3 = {0,0,0,0};
#pragma unroll 2
  for (int k = 0; k < XD; k += 4) {
    float4 x_0 = *(const float4*)(xp + 0 * XD + k);
    float4 x_1 = *(const float4*)(xp + 1 * XD + k);
    float4 x_2 = *(const float4*)(xp + 2 * XD + k);
    float4 x_3 = *(const float4*)(xp + 3 * XD + k);
    float4 k_0 = *(const float4*)&kt[k + 0][tx * 4];
    float4 k_1 = *(const float4*)&kt[k + 1][tx * 4];
    float4 k_2 = *(const float4*)&kt[k + 2][tx * 4];
    float4 k_3 = *(const float4*)&kt[k + 3][tx * 4];
    FMA4(acc0, x_0.x, k_0) FMA4(acc0, x_0.y, k_1) FMA4(acc0, x_0.z, k_2) FMA4(acc0, x_0.w, k_3)
    FMA4(acc1, x_1.x, k_0) FMA4(acc1, x_1.y, k_1) FMA4(acc1, x_1.z, k_2) FMA4(acc1, x_1.w, k_3)
    FMA4(acc2, x_2.x, k_0) FMA4(acc2, x_2.y, k_1) FMA4(acc2, x_2.z, k_2) FMA4(acc2, x_2.w, k_3)
    FMA4(acc3, x_3.x, k_0) FMA4(acc3, x_3.y, k_1) FMA4(acc3, x_3.z, k_2) FMA4(acc3, x_3.w, k_3)
  }
  float4 cq = *(float4*)&cvs[tx * 4];
  acc0.x += cq.x; acc0.y += cq.y; acc0.z += cq.z; acc0.w += cq.w;
  acc1.x += cq.x; acc1.y += cq.y; acc1.z += cq.z; acc1.w += cq.w;
  acc2.x += cq.x; acc2.y += cq.y; acc2.z += cq.z; acc2.w += cq.w;
  acc3.x += cq.x; acc3.y += cq.y; acc3.z += cq.z; acc3.w += cq.w;
  *(float4*)(out + (r0 + 0) * UD + tx * 4) = acc0;
  *(float4*)(out + (r0 + 1) * UD + tx * 4) = acc1;
  *(float4*)(out + (r0 + 2) * UD + tx * 4) = acc2;
  *(float4*)(out + (r0 + 3) * UD + tx * 4) = acc3;
}

extern "C" void kernel_launch(void* const* d_in, const int* in_sizes, int n_in,
                              void* d_out, int out_size, void* d_ws, size_t ws_size,
                              hipStream_t stream) {
  const float* x0   = (const float*)d_in[0];
  const float* W    = (const float*)d_in[1];
  const float* bphi = (const float*)d_in[2];
  const float* xg   = (const float*)d_in[3];
  const float* A    = (const float*)d_in[4];
  const float* B    = (const float*)d_in[5];
  const float* ql   = (const float*)d_in[6];
  const float* rl   = (const float*)d_in[7];
  float* ws  = (float*)d_ws;
  float* out = (float*)d_out;

  hipLaunchKernelGGL(k_init, dim3(64), dim3(256), 0, stream, W, bphi, xg, ql, rl, ws);
  for (int it = 0; it < TH; ++it) {
    int last = (it == TH - 1) ? 1 : 0;
    hipLaunchKernelGGL(k_ph1, dim3(64), dim3(256), 0, stream, A, B, ws);
    hipLaunchKernelGGL(k_ph2, dim3(65), dim3(256), 0, stream, A, B, ws, last);
    hipLaunchKernelGGL(k_ph3, dim3(64), dim3(256), 0, stream, ws, last);
  }
  hipLaunchKernelGGL(k_fin, dim3(65), dim3(256), 0, stream, W, bphi, ws);
  int rows = in_sizes[0] / XD;
  int nblk = rows / 64;
  hipLaunchKernelGGL(k_batch, dim3(nblk), dim3(256), 0, stream, x0, ws, out);
}